// Round 1
// baseline (263.457 us; speedup 1.0000x reference)
//
#include <hip/hip_runtime.h>
#include <math.h>

#define L      2048
#define DDIM   512
#define NBATCH 8
#define BM     128
#define BN     128
#define BK     16
#define NTILE  (L / BM)                 // 16
#define NPAIR  (NTILE * (NTILE + 1) / 2) // 136
#define TOTAL_BLOCKS (NBATCH * NPAIR)    // 1088

#define ALPHA  0.1f
#define BETA   0.3f
#define MARGIN 2.0f

// ---------------------------------------------------------------------------
// Kernel 1: per-row squared norms. One wave (64 lanes) per row of 512 floats.
// ---------------------------------------------------------------------------
__global__ __launch_bounds__(64) void sq_kernel(const float* __restrict__ pred,
                                                float* __restrict__ sq) {
    int row = blockIdx.x;                       // 0 .. NBATCH*L-1
    const float* p = pred + (size_t)row * DDIM;
    int lane = threadIdx.x;                     // 0..63, 8 floats each
    float4 v0 = *(const float4*)(p + lane * 8);
    float4 v1 = *(const float4*)(p + lane * 8 + 4);
    float s = v0.x * v0.x + v0.y * v0.y + v0.z * v0.z + v0.w * v0.w
            + v1.x * v1.x + v1.y * v1.y + v1.z * v1.z + v1.w * v1.w;
    #pragma unroll
    for (int off = 32; off > 0; off >>= 1) s += __shfl_down(s, off);
    if (lane == 0) sq[row] = s;
}

// ---------------------------------------------------------------------------
// Kernel 2: fused tile GEMM (inner products) + loss + per-block reduction.
// Tile-pair (tj<=tk) symmetry: off-diagonal tiles weighted 2x.
// 256 threads, 128x128 tile, 8x8 micro-tile per thread, BK=16.
// ---------------------------------------------------------------------------
__global__ __launch_bounds__(256) void loss_kernel(const float* __restrict__ pred,
                                                   const int*   __restrict__ seg,
                                                   const float* __restrict__ sq,
                                                   double*      __restrict__ partials) {
    __shared__ float As[BK][BM + 4];   // transposed: As[d][row]
    __shared__ float Bs[BK][BN + 4];

    int bid = blockIdx.x;
    int n = bid / NPAIR;
    int p = bid % NPAIR;
    // decode (tj, tk) with tj <= tk
    int tj = 0;
    while (true) {
        int rl = NTILE - tj;
        if (p < rl) break;
        p -= rl;
        ++tj;
    }
    int tk = tj + p;
    int j0 = tj * BM, k0 = tk * BN;

    const float* base = pred + (size_t)n * L * DDIM;
    int t  = threadIdx.x;
    int tx = t & 15;        // 0..15  (cols)
    int ty = t >> 4;        // 0..15  (rows)

    // staging indices: each thread loads 8 consecutive floats of one row
    int lr = t >> 1;          // 0..127 row within tile
    int lc = (t & 1) * 8;     // 0 or 8 col offset

    float acc[8][8];
    #pragma unroll
    for (int i = 0; i < 8; ++i)
        #pragma unroll
        for (int j = 0; j < 8; ++j) acc[i][j] = 0.0f;

    const float* ga = base + (size_t)(j0 + lr) * DDIM + lc;
    const float* gb = base + (size_t)(k0 + lr) * DDIM + lc;

    for (int kk = 0; kk < DDIM; kk += BK) {
        float4 a0 = *(const float4*)(ga + kk);
        float4 a1 = *(const float4*)(ga + kk + 4);
        float4 b0 = *(const float4*)(gb + kk);
        float4 b1 = *(const float4*)(gb + kk + 4);
        __syncthreads();   // previous iteration finished reading LDS
        As[lc + 0][lr] = a0.x; As[lc + 1][lr] = a0.y;
        As[lc + 2][lr] = a0.z; As[lc + 3][lr] = a0.w;
        As[lc + 4][lr] = a1.x; As[lc + 5][lr] = a1.y;
        As[lc + 6][lr] = a1.z; As[lc + 7][lr] = a1.w;
        Bs[lc + 0][lr] = b0.x; Bs[lc + 1][lr] = b0.y;
        Bs[lc + 2][lr] = b0.z; Bs[lc + 3][lr] = b0.w;
        Bs[lc + 4][lr] = b1.x; Bs[lc + 5][lr] = b1.y;
        Bs[lc + 6][lr] = b1.z; Bs[lc + 7][lr] = b1.w;
        __syncthreads();
        #pragma unroll
        for (int d = 0; d < BK; ++d) {
            float4 xa0 = *(const float4*)&As[d][ty * 8];
            float4 xa1 = *(const float4*)&As[d][ty * 8 + 4];
            float4 xb0 = *(const float4*)&Bs[d][tx * 8];
            float4 xb1 = *(const float4*)&Bs[d][tx * 8 + 4];
            float av[8] = {xa0.x, xa0.y, xa0.z, xa0.w, xa1.x, xa1.y, xa1.z, xa1.w};
            float bv[8] = {xb0.x, xb0.y, xb0.z, xb0.w, xb1.x, xb1.y, xb1.z, xb1.w};
            #pragma unroll
            for (int i = 0; i < 8; ++i)
                #pragma unroll
                for (int j = 0; j < 8; ++j)
                    acc[i][j] = fmaf(av[i], bv[j], acc[i][j]);
        }
    }

    // ------------------- fused loss epilogue -------------------
    const int*   segb = seg + n * L;
    const float* sqb  = sq + n * L;
    float sqj[8], sqk[8];
    int   sgj[8], sgk[8];
    #pragma unroll
    for (int i = 0; i < 8; ++i) {
        int j = j0 + ty * 8 + i;
        int k = k0 + tx * 8 + i;
        sqj[i] = sqb[j]; sgj[i] = segb[j];
        sqk[i] = sqb[k]; sgk[i] = segb[k];
    }

    double lsum = 0.0;
    #pragma unroll
    for (int i = 0; i < 8; ++i) {
        #pragma unroll
        for (int j = 0; j < 8; ++j) {
            float d2 = fmaxf(sqj[i] + sqk[j] - 2.0f * acc[i][j], 0.0f);
            float v;
            if (sgj[i] == sgk[j]) {
                v = ALPHA * d2;
            } else {
                float dist = sqrtf(d2);
                float h = fmaxf(MARGIN - dist, 0.0f);
                v = BETA * h * h;
            }
            lsum += (double)v;
        }
    }
    double w = (tj == tk) ? 1.0 : 2.0;

    __shared__ double red[256];
    red[t] = lsum * w;
    __syncthreads();
    #pragma unroll
    for (int s = 128; s > 0; s >>= 1) {
        if (t < s) red[t] += red[t + s];
        __syncthreads();
    }
    if (t == 0) partials[blockIdx.x] = red[0];
}

// ---------------------------------------------------------------------------
// Kernel 3: deterministic final reduction of block partials -> mean.
// ---------------------------------------------------------------------------
__global__ __launch_bounds__(256) void reduce_kernel(const double* __restrict__ partials,
                                                     float* __restrict__ out,
                                                     int nPart, double invCount) {
    __shared__ double red[256];
    int t = threadIdx.x;
    double s = 0.0;
    for (int i = t; i < nPart; i += 256) s += partials[i];
    red[t] = s;
    __syncthreads();
    #pragma unroll
    for (int k = 128; k > 0; k >>= 1) {
        if (t < k) red[t] += red[t + k];
        __syncthreads();
    }
    if (t == 0) out[0] = (float)(red[0] * invCount);
}

extern "C" void kernel_launch(void* const* d_in, const int* in_sizes, int n_in,
                              void* d_out, int out_size, void* d_ws, size_t ws_size,
                              hipStream_t stream) {
    const float* pred = (const float*)d_in[0];
    const int*   seg  = (const int*)d_in[1];   // jax x64 disabled -> int32
    float* out = (float*)d_out;

    double* partials = (double*)d_ws;                          // 1088 * 8 B
    float*  sq       = (float*)((char*)d_ws + 65536);          // 8*2048 * 4 B

    sq_kernel<<<NBATCH * L, 64, 0, stream>>>(pred, sq);
    loss_kernel<<<TOTAL_BLOCKS, 256, 0, stream>>>(pred, seg, sq, partials);
    reduce_kernel<<<1, 256, 0, stream>>>(partials, out, TOTAL_BLOCKS,
                                         1.0 / (double)((size_t)NBATCH * L * L));
}

// Round 2
// 130.460 us; speedup vs baseline: 2.0194x; 2.0194x over previous
//
#include <hip/hip_runtime.h>
#include <math.h>

#define L      2048
#define DDIM   512
#define NBATCH 8
#define BM     128
#define BN     128
#define BK     64
#define NTILE  (L / BM)                  // 16
#define NPAIR  (NTILE * (NTILE + 1) / 2) // 136
#define TOTAL_BLOCKS (NBATCH * NPAIR)    // 1088

#define ALPHA  0.1f
#define BETA   0.3f
#define MARGIN 2.0f

typedef __attribute__((ext_vector_type(8))) short bf16x8;
typedef __attribute__((ext_vector_type(4))) float f32x4;

#define GLOAD_LDS16(g, l) __builtin_amdgcn_global_load_lds(              \
    (const __attribute__((address_space(1))) unsigned int*)(g),          \
    (__attribute__((address_space(3))) unsigned int*)(l), 16, 0, 0)

__device__ __forceinline__ unsigned short f2bf_rne(float x) {
    unsigned u = __float_as_uint(x);
    unsigned r = (u + 0x7FFFu + ((u >> 16) & 1u)) >> 16;
    return (unsigned short)r;
}
__device__ __forceinline__ float bf2f(unsigned short h) {
    return __uint_as_float(((unsigned)h) << 16);
}

// ---------------------------------------------------------------------------
// Kernel 1: fp32 -> (hi, lo) bf16 split + per-row squared norms (exact fp32).
// 256 threads = 4 waves, one wave per row of 512.
// ---------------------------------------------------------------------------
__global__ __launch_bounds__(256) void conv_kernel(const float* __restrict__ pred,
                                                   unsigned short* __restrict__ hi,
                                                   unsigned short* __restrict__ lo,
                                                   float* __restrict__ sq) {
    int w    = threadIdx.x >> 6;
    int lane = threadIdx.x & 63;
    int row  = blockIdx.x * 4 + w;
    const float* p = pred + (size_t)row * DDIM + lane * 8;
    float4 v0 = *(const float4*)(p);
    float4 v1 = *(const float4*)(p + 4);
    float vals[8] = {v0.x, v0.y, v0.z, v0.w, v1.x, v1.y, v1.z, v1.w};
    unsigned short hb[8], lb[8];
    float s = 0.0f;
    #pragma unroll
    for (int i = 0; i < 8; ++i) {
        float x = vals[i];
        s = fmaf(x, x, s);
        unsigned short h = f2bf_rne(x);
        float rem = x - bf2f(h);
        hb[i] = h;
        lb[i] = f2bf_rne(rem);
    }
    size_t o = (size_t)row * DDIM + lane * 8;
    *(ushort4*)(hi + o)     = make_ushort4(hb[0], hb[1], hb[2], hb[3]);
    *(ushort4*)(hi + o + 4) = make_ushort4(hb[4], hb[5], hb[6], hb[7]);
    *(ushort4*)(lo + o)     = make_ushort4(lb[0], lb[1], lb[2], lb[3]);
    *(ushort4*)(lo + o + 4) = make_ushort4(lb[4], lb[5], lb[6], lb[7]);
    #pragma unroll
    for (int off = 32; off > 0; off >>= 1) s += __shfl_down(s, off);
    if (lane == 0) sq[row] = s;
}

// ---------------------------------------------------------------------------
// Kernel 2: split-bf16 MFMA tile GEMM + fused loss + per-block reduction.
// 128x128 tile, 4 waves (2x2 of 64x64), mfma_f32_16x16x32_bf16, BK=64.
// Phases: Hi*Hi^T + Hi*Lo^T + Lo*Hi^T (Lo*Lo dropped, ~2^-18 rel).
// LDS staged with global_load_lds(16B); XOR chunk-swizzle on global source
// so stride-128B ds_read_b128 fragment reads are bank-conflict-free.
// ---------------------------------------------------------------------------
__global__ __launch_bounds__(256) void loss_kernel(const unsigned short* __restrict__ hi,
                                                   const unsigned short* __restrict__ lo,
                                                   const int*   __restrict__ seg,
                                                   const float* __restrict__ sq,
                                                   double*      __restrict__ partials) {
    __shared__ unsigned short As[BM * BK];   // [row][k], 128B rows, swizzled
    __shared__ unsigned short Bs[BN * BK];
    __shared__ double red[256];

    int bid = blockIdx.x;
    int n = bid / NPAIR;
    int p = bid % NPAIR;
    int tj = 0;
    while (true) {
        int rl = NTILE - tj;
        if (p < rl) break;
        p -= rl;
        ++tj;
    }
    int tk = tj + p;
    int j0 = tj * BM, k0 = tk * BN;

    int t    = threadIdx.x;
    int w    = t >> 6;
    int lane = t & 63;
    int wr   = w >> 1, wc = w & 1;          // wave -> 64x64 quadrant

    // staging: inst covers 8 rows; lane -> (row=lane>>3, chunk=lane&7)
    int srow   = lane >> 3;                  // 0..7
    int schunk = lane & 7;                   // 16B chunk in row
    int pchunk = schunk ^ srow;              // pre-swizzled source chunk

    const unsigned short* baseHi = hi + (size_t)n * L * DDIM;
    const unsigned short* baseLo = lo + (size_t)n * L * DDIM;

    f32x4 acc[4][4];
    #pragma unroll
    for (int m = 0; m < 4; ++m)
        #pragma unroll
        for (int nn = 0; nn < 4; ++nn) acc[m][nn] = (f32x4){0.f, 0.f, 0.f, 0.f};

    int lrow = lane & 15;
    int lq   = lane >> 4;                    // 0..3

    #pragma unroll 1
    for (int phase = 0; phase < 3; ++phase) {
        const unsigned short* SA = (phase == 2) ? baseLo : baseHi;
        const unsigned short* SB = (phase == 1) ? baseLo : baseHi;
        #pragma unroll 1
        for (int kk = 0; kk < DDIM; kk += BK) {
            __syncthreads();   // previous iteration done reading LDS
            #pragma unroll
            for (int q = 0; q < 4; ++q) {
                int i = w * 4 + q;           // inst 0..15, rows i*8..i*8+7
                int r = i * 8 + srow;
                GLOAD_LDS16(SA + (size_t)(j0 + r) * DDIM + kk + (pchunk << 3),
                            &As[i * 512]);
            }
            #pragma unroll
            for (int q = 0; q < 4; ++q) {
                int i = w * 4 + q;
                int r = i * 8 + srow;
                GLOAD_LDS16(SB + (size_t)(k0 + r) * DDIM + kk + (pchunk << 3),
                            &Bs[i * 512]);
            }
            __syncthreads();   // compiler drains vmcnt before s_barrier

            #pragma unroll
            for (int k2 = 0; k2 < 2; ++k2) {           // two K=32 steps
                bf16x8 af[4], bfr[4];
                #pragma unroll
                for (int m = 0; m < 4; ++m) {
                    int r  = wr * 64 + m * 16 + lrow;
                    int kc = k2 * 4 + lq;              // logical chunk
                    af[m] = *(const bf16x8*)&As[r * 64 + ((kc ^ (r & 7)) << 3)];
                }
                #pragma unroll
                for (int nn = 0; nn < 4; ++nn) {
                    int r  = wc * 64 + nn * 16 + lrow;
                    int kc = k2 * 4 + lq;
                    bfr[nn] = *(const bf16x8*)&Bs[r * 64 + ((kc ^ (r & 7)) << 3)];
                }
                #pragma unroll
                for (int m = 0; m < 4; ++m)
                    #pragma unroll
                    for (int nn = 0; nn < 4; ++nn)
                        acc[m][nn] = __builtin_amdgcn_mfma_f32_16x16x32_bf16(
                            af[m], bfr[nn], acc[m][nn], 0, 0, 0);
            }
        }
    }

    // ------------------- fused loss epilogue -------------------
    // C/D layout: col = lane&15, row = (lane>>4)*4 + reg
    const int*   segb = seg + n * L;
    const float* sqb  = sq + n * L;

    float sqk[4]; int sgk[4];
    #pragma unroll
    for (int nn = 0; nn < 4; ++nn) {
        int k = k0 + wc * 64 + nn * 16 + lrow;
        sqk[nn] = sqb[k]; sgk[nn] = segb[k];
    }
    float sqj[4][4]; int sgj[4][4];
    #pragma unroll
    for (int m = 0; m < 4; ++m)
        #pragma unroll
        for (int reg = 0; reg < 4; ++reg) {
            int j = j0 + wr * 64 + m * 16 + lq * 4 + reg;
            sqj[m][reg] = sqb[j]; sgj[m][reg] = segb[j];
        }

    float lsum = 0.0f;
    #pragma unroll
    for (int m = 0; m < 4; ++m)
        #pragma unroll
        for (int nn = 0; nn < 4; ++nn)
            #pragma unroll
            for (int reg = 0; reg < 4; ++reg) {
                float inner = acc[m][nn][reg];
                float d2 = fmaxf(sqj[m][reg] + sqk[nn] - 2.0f * inner, 0.0f);
                float v;
                if (sgj[m][reg] == sgk[nn]) {
                    v = ALPHA * d2;
                } else {
                    float dist = sqrtf(d2);
                    float h = fmaxf(MARGIN - dist, 0.0f);
                    v = BETA * h * h;
                }
                lsum += v;
            }

    double wgt = (tj == tk) ? 1.0 : 2.0;
    red[t] = (double)lsum * wgt;
    __syncthreads();
    #pragma unroll
    for (int s = 128; s > 0; s >>= 1) {
        if (t < s) red[t] += red[t + s];
        __syncthreads();
    }
    if (t == 0) partials[blockIdx.x] = red[0];
}

// ---------------------------------------------------------------------------
// Kernel 3: deterministic final reduction -> mean.
// ---------------------------------------------------------------------------
__global__ __launch_bounds__(256) void reduce_kernel(const double* __restrict__ partials,
                                                     float* __restrict__ out,
                                                     int nPart, double invCount) {
    __shared__ double red[256];
    int t = threadIdx.x;
    double s = 0.0;
    for (int i = t; i < nPart; i += 256) s += partials[i];
    red[t] = s;
    __syncthreads();
    #pragma unroll
    for (int k = 128; k > 0; k >>= 1) {
        if (t < k) red[t] += red[t + k];
        __syncthreads();
    }
    if (t == 0) out[0] = (float)(red[0] * invCount);
}

extern "C" void kernel_launch(void* const* d_in, const int* in_sizes, int n_in,
                              void* d_out, int out_size, void* d_ws, size_t ws_size,
                              hipStream_t stream) {
    const float* pred = (const float*)d_in[0];
    const int*   seg  = (const int*)d_in[1];   // x64 disabled -> int32 (verified r1)
    float* out = (float*)d_out;

    const size_t HALF = (size_t)NBATCH * L * DDIM;          // 8.39M elems
    unsigned short* hi = (unsigned short*)d_ws;              // 16.78 MB
    unsigned short* lo = hi + HALF;                          // 16.78 MB
    float*  sq         = (float*)(lo + HALF);                // 64 KB
    double* partials   = (double*)(sq + NBATCH * L);         // 8.7 KB

    conv_kernel<<<NBATCH * L / 4, 256, 0, stream>>>(pred, hi, lo, sq);
    loss_kernel<<<TOTAL_BLOCKS, 256, 0, stream>>>(hi, lo, seg, sq, partials);
    reduce_kernel<<<1, 256, 0, stream>>>(partials, out, TOTAL_BLOCKS,
                                         1.0 / (double)((size_t)NBATCH * L * L));
}

// Round 3
// 93.018 us; speedup vs baseline: 2.8323x; 1.4025x over previous
//
#include <hip/hip_runtime.h>
#include <math.h>

#define L      2048
#define DDIM   512
#define NBATCH 8
#define BM     128
#define BN     128
#define BK     64
#define NTILE  (L / BM)                  // 16
#define NPAIR  (NTILE * (NTILE + 1) / 2) // 136
#define TOTAL_BLOCKS (NBATCH * NPAIR)    // 1088

#define ALPHA  0.1f
#define BETA   0.3f
#define MARGIN 2.0f

typedef __attribute__((ext_vector_type(8))) short bf16x8;
typedef __attribute__((ext_vector_type(4))) float f32x4;

#define GLOAD_LDS16(g, l) __builtin_amdgcn_global_load_lds(              \
    (const __attribute__((address_space(1))) unsigned int*)(g),          \
    (__attribute__((address_space(3))) unsigned int*)(l), 16, 0, 0)

__device__ __forceinline__ unsigned short f2bf_rne(float x) {
    unsigned u = __float_as_uint(x);
    unsigned r = (u + 0x7FFFu + ((u >> 16) & 1u)) >> 16;
    return (unsigned short)r;
}
__device__ __forceinline__ float bf2f(unsigned short h) {
    return __uint_as_float(((unsigned)h) << 16);
}

// ---------------------------------------------------------------------------
// Kernel 1: fp32 -> (hi, lo) bf16 split + per-row squared norms (exact fp32).
// ---------------------------------------------------------------------------
__global__ __launch_bounds__(256) void conv_kernel(const float* __restrict__ pred,
                                                   unsigned short* __restrict__ hi,
                                                   unsigned short* __restrict__ lo,
                                                   float* __restrict__ sq) {
    int w    = threadIdx.x >> 6;
    int lane = threadIdx.x & 63;
    int row  = blockIdx.x * 4 + w;
    const float* p = pred + (size_t)row * DDIM + lane * 8;
    float4 v0 = *(const float4*)(p);
    float4 v1 = *(const float4*)(p + 4);
    float vals[8] = {v0.x, v0.y, v0.z, v0.w, v1.x, v1.y, v1.z, v1.w};
    unsigned short hb[8], lb[8];
    float s = 0.0f;
    #pragma unroll
    for (int i = 0; i < 8; ++i) {
        float x = vals[i];
        s = fmaf(x, x, s);
        unsigned short h = f2bf_rne(x);
        float rem = x - bf2f(h);
        hb[i] = h;
        lb[i] = f2bf_rne(rem);
    }
    size_t o = (size_t)row * DDIM + lane * 8;
    *(ushort4*)(hi + o)     = make_ushort4(hb[0], hb[1], hb[2], hb[3]);
    *(ushort4*)(hi + o + 4) = make_ushort4(hb[4], hb[5], hb[6], hb[7]);
    *(ushort4*)(lo + o)     = make_ushort4(lb[0], lb[1], lb[2], lb[3]);
    *(ushort4*)(lo + o + 4) = make_ushort4(lb[4], lb[5], lb[6], lb[7]);
    #pragma unroll
    for (int off = 32; off > 0; off >>= 1) s += __shfl_down(s, off);
    if (lane == 0) sq[row] = s;
}

// ---------------------------------------------------------------------------
// Kernel 2: merged split-bf16 MFMA GEMM (Hi*Hi + Hi*Lo + Lo*Hi in ONE K-sweep)
// + fused loss + per-block reduction.
// 128x128 tile, 4 waves (2x2 of 64x64), mfma_f32_16x16x32_bf16, BK=64.
// LDS: 4 tiles (Ahi, Alo, Bhi, Blo) x 16KB = 64KB, single-buffered.
// Batch->XCD swizzle: blockIdx.x & 7 = batch, so each XCD's L2 holds exactly
// one batch's hi+lo (4.19 MB vs 4 MiB L2) -> near-zero HBM re-fetch.
// ---------------------------------------------------------------------------
__global__ __launch_bounds__(256) void loss_kernel(const unsigned short* __restrict__ hi,
                                                   const unsigned short* __restrict__ lo,
                                                   const int*   __restrict__ seg,
                                                   const float* __restrict__ sq,
                                                   double*      __restrict__ partials) {
    __shared__ unsigned short smem[4 * BM * BK];   // 64 KB: AHI|ALO|BHI|BLO
    unsigned short* AHI = smem;
    unsigned short* ALO = smem + 1 * BM * BK;
    unsigned short* BHI = smem + 2 * BM * BK;
    unsigned short* BLO = smem + 3 * BM * BK;

    int bid = blockIdx.x;
    int n = bid & 7;            // batch -> XCD (round-robin assumption)
    int p = bid >> 3;           // 0..135 tile-pair index
    int tj = 0;
    while (true) {
        int rl = NTILE - tj;
        if (p < rl) break;
        p -= rl;
        ++tj;
    }
    int tk = tj + p;
    int j0 = tj * BM, k0 = tk * BN;

    int t    = threadIdx.x;
    int w    = t >> 6;
    int lane = t & 63;
    int wr   = w >> 1, wc = w & 1;          // wave -> 64x64 quadrant

    // staging: inst i covers rows i*8..i*8+7; lane -> (row=lane>>3, chunk=lane&7)
    int srow   = lane >> 3;
    int schunk = lane & 7;
    int pchunk = schunk ^ srow;              // pre-swizzled source chunk

    const unsigned short* baseHi = hi + (size_t)n * L * DDIM;
    const unsigned short* baseLo = lo + (size_t)n * L * DDIM;

    f32x4 acc[4][4];
    #pragma unroll
    for (int m = 0; m < 4; ++m)
        #pragma unroll
        for (int nn = 0; nn < 4; ++nn) acc[m][nn] = (f32x4){0.f, 0.f, 0.f, 0.f};

    int lrow = lane & 15;
    int lq   = lane >> 4;                    // 0..3

    #pragma unroll 1
    for (int kk = 0; kk < DDIM; kk += BK) {
        __syncthreads();   // previous iteration done reading LDS
        #pragma unroll
        for (int q = 0; q < 4; ++q) {
            int i = w * 4 + q;               // inst 0..15
            int r = i * 8 + srow;
            size_t goff = (size_t)(j0 + r) * DDIM + kk + (pchunk << 3);
            GLOAD_LDS16(baseHi + goff, &AHI[i * 512]);
            GLOAD_LDS16(baseLo + goff, &ALO[i * 512]);
        }
        #pragma unroll
        for (int q = 0; q < 4; ++q) {
            int i = w * 4 + q;
            int r = i * 8 + srow;
            size_t goff = (size_t)(k0 + r) * DDIM + kk + (pchunk << 3);
            GLOAD_LDS16(baseHi + goff, &BHI[i * 512]);
            GLOAD_LDS16(baseLo + goff, &BLO[i * 512]);
        }
        __syncthreads();   // vmcnt drained by compiler before barrier

        #pragma unroll
        for (int k2 = 0; k2 < 2; ++k2) {           // two K=32 steps
            bf16x8 ah[4], al[4], bh[4], bl[4];
            #pragma unroll
            for (int m = 0; m < 4; ++m) {
                int r   = wr * 64 + m * 16 + lrow;
                int kc  = k2 * 4 + lq;
                int off = r * 64 + ((kc ^ (r & 7)) << 3);
                ah[m] = *(const bf16x8*)&AHI[off];
                al[m] = *(const bf16x8*)&ALO[off];
            }
            #pragma unroll
            for (int nn = 0; nn < 4; ++nn) {
                int r   = wc * 64 + nn * 16 + lrow;
                int kc  = k2 * 4 + lq;
                int off = r * 64 + ((kc ^ (r & 7)) << 3);
                bh[nn] = *(const bf16x8*)&BHI[off];
                bl[nn] = *(const bf16x8*)&BLO[off];
            }
            #pragma unroll
            for (int m = 0; m < 4; ++m)
                #pragma unroll
                for (int nn = 0; nn < 4; ++nn) {
                    acc[m][nn] = __builtin_amdgcn_mfma_f32_16x16x32_bf16(
                        ah[m], bh[nn], acc[m][nn], 0, 0, 0);
                    acc[m][nn] = __builtin_amdgcn_mfma_f32_16x16x32_bf16(
                        ah[m], bl[nn], acc[m][nn], 0, 0, 0);
                    acc[m][nn] = __builtin_amdgcn_mfma_f32_16x16x32_bf16(
                        al[m], bh[nn], acc[m][nn], 0, 0, 0);
                }
        }
    }

    // ------------------- fused loss epilogue -------------------
    // C/D layout: col = lane&15, row = (lane>>4)*4 + reg
    const int*   segb = seg + n * L;
    const float* sqb  = sq + n * L;

    float sqk[4]; int sgk[4];
    #pragma unroll
    for (int nn = 0; nn < 4; ++nn) {
        int k = k0 + wc * 64 + nn * 16 + lrow;
        sqk[nn] = sqb[k]; sgk[nn] = segb[k];
    }
    float sqj[4][4]; int sgj[4][4];
    #pragma unroll
    for (int m = 0; m < 4; ++m)
        #pragma unroll
        for (int reg = 0; reg < 4; ++reg) {
            int j = j0 + wr * 64 + m * 16 + lq * 4 + reg;
            sqj[m][reg] = sqb[j]; sgj[m][reg] = segb[j];
        }

    float lsum = 0.0f;
    #pragma unroll
    for (int m = 0; m < 4; ++m)
        #pragma unroll
        for (int nn = 0; nn < 4; ++nn)
            #pragma unroll
            for (int reg = 0; reg < 4; ++reg) {
                float inner = acc[m][nn][reg];
                float d2 = fmaxf(sqj[m][reg] + sqk[nn] - 2.0f * inner, 0.0f);
                float v;
                if (sgj[m][reg] == sgk[nn]) {
                    v = ALPHA * d2;
                } else {
                    float dist = sqrtf(d2);
                    float h = fmaxf(MARGIN - dist, 0.0f);
                    v = BETA * h * h;
                }
                lsum += v;
            }

    double wgt = (tj == tk) ? 1.0 : 2.0;
    __syncthreads();                       // all waves done reading LDS tiles
    double* red = (double*)smem;           // alias reduction onto tile LDS
    red[t] = (double)lsum * wgt;
    __syncthreads();
    #pragma unroll
    for (int s = 128; s > 0; s >>= 1) {
        if (t < s) red[t] += red[t + s];
        __syncthreads();
    }
    if (t == 0) partials[blockIdx.x] = red[0];
}

// ---------------------------------------------------------------------------
// Kernel 3: deterministic final reduction -> mean.
// ---------------------------------------------------------------------------
__global__ __launch_bounds__(256) void reduce_kernel(const double* __restrict__ partials,
                                                     float* __restrict__ out,
                                                     int nPart, double invCount) {
    __shared__ double red[256];
    int t = threadIdx.x;
    double s = 0.0;
    for (int i = t; i < nPart; i += 256) s += partials[i];
    red[t] = s;
    __syncthreads();
    #pragma unroll
    for (int k = 128; k > 0; k >>= 1) {
        if (t < k) red[t] += red[t + k];
        __syncthreads();
    }
    if (t == 0) out[0] = (float)(red[0] * invCount);
}

extern "C" void kernel_launch(void* const* d_in, const int* in_sizes, int n_in,
                              void* d_out, int out_size, void* d_ws, size_t ws_size,
                              hipStream_t stream) {
    const float* pred = (const float*)d_in[0];
    const int*   seg  = (const int*)d_in[1];
    float* out = (float*)d_out;

    const size_t HALF = (size_t)NBATCH * L * DDIM;
    unsigned short* hi = (unsigned short*)d_ws;
    unsigned short* lo = hi + HALF;
    float*  sq         = (float*)(lo + HALF);
    double* partials   = (double*)(sq + NBATCH * L);

    conv_kernel<<<NBATCH * L / 4, 256, 0, stream>>>(pred, hi, lo, sq);
    loss_kernel<<<TOTAL_BLOCKS, 256, 0, stream>>>(hi, lo, seg, sq, partials);
    reduce_kernel<<<1, 256, 0, stream>>>(partials, out, TOTAL_BLOCKS,
                                         1.0 / (double)((size_t)NBATCH * L * L));
}